// Round 3
// baseline (1106.474 us; speedup 1.0000x reference)
//
#include <hip/hip_runtime.h>
#include <math.h>

#define NB 64
#define NN 4096
#define ND 256
#define NS 256
#define NK 8
#define NH 512
#define NROW (NB*NN)
#define NSLOT (NB*NK)
#define EPSA 1e-8f
#define NCG 32            // n-chunks per batch in attn (128 n each)

typedef unsigned short u16;
typedef unsigned int   u32;
typedef __bf16 bf16x8 __attribute__((ext_vector_type(8)));
typedef float  f32x4  __attribute__((ext_vector_type(4)));

__device__ __forceinline__ float bf2f(u16 u) {
  union { u32 i; float f; } v; v.i = ((u32)u) << 16; return v.f;
}
__device__ __forceinline__ u16 f2bf(float f) {
  union { float f; u32 i; } v; v.f = f;
  u32 x = v.i;
  return (u16)((x + 0x7FFFu + ((x >> 16) & 1u)) >> 16);
}

// ---------------- workspace layout (bytes) ----------------
#define OFF_KG     0ULL            // k  [262144][256] bf16 = 134217728
#define OFF_VTG    134217728ULL    // vT [64][256][4096] bf16 = 134217728
#define OFF_SLOTS  268435456ULL    // 512*256 f32
#define OFF_QBF    268959744ULL    // 512*256 bf16
#define OFF_UPDP   269221888ULL    // 64*32*8*256 f32 = 16777216
#define OFF_SUMSP  285999104ULL    // 64*32*8 f32 = 65536
#define OFF_WC     286064640ULL    // 512*256 bf16
#define OFF_WQT    286326784ULL    // 256*256 f32
#define OFF_WIHT   286588928ULL    // 256*768 f32
#define OFF_WHHT   287375360ULL    // 256*768 f32
#define OFF_W1T    288161792ULL    // 256*512 f32
#define OFF_W2T    288686080ULL    // 512*256 f32 (end ~289 MB)

// ---------------- K0: weight prep (unchanged, proven) ----------------
__global__ __launch_bounds__(256) void prep_kernel(
    const float* __restrict__ Wq, const float* __restrict__ Wk, const float* __restrict__ Wv,
    const float* __restrict__ Wih, const float* __restrict__ Whh,
    const float* __restrict__ W1, const float* __restrict__ W2,
    u16* __restrict__ Wc, float* __restrict__ WqT, float* __restrict__ WihT,
    float* __restrict__ WhhT, float* __restrict__ W1T, float* __restrict__ W2T)
{
  int idx = blockIdx.x * 256 + threadIdx.x;   // 768*256
  if (idx < 512*256) {
    int j = idx >> 8, d = idx & 255;
    float w = (j < 256) ? Wk[idx] * 0.0625f : Wv[idx - 65536];
    Wc[idx] = f2bf(w);
    W1T[d*512 + j] = W1[idx];
  }
  if (idx < 256*256) {
    int j = idx >> 8, d = idx & 255;
    WqT[d*256 + j] = Wq[idx];
  }
  if (idx < 768*256) {
    int j = idx >> 8, d = idx & 255;
    WihT[d*768 + j] = Wih[idx];
    WhhT[d*768 + j] = Whh[idx];
  }
  if (idx < 256*512) {
    int j = idx >> 9, h = idx & 511;
    W2T[h*256 + j] = W2[idx];
  }
}

// ---------------- K1: slots init ----------------
__global__ __launch_bounds__(256) void slots_init_kernel(
    const float* __restrict__ noise, const float* __restrict__ mu,
    const float* __restrict__ lsig, float* __restrict__ slots)
{
  int idx = blockIdx.x * 256 + threadIdx.x;
  int s = idx & 255;
  slots[idx] = mu[s] + expf(lsig[s]) * noise[idx];
}

// ---------------- K2: fused LN + kv GEMM v3 ----------------
// 64 rows/block. LDS: single 32KB buffer = swizzled LN(A) tile, later reused
// as vT staging. B (Wc) read once per block straight from L2. 3 barriers total.
__global__ __launch_bounds__(256, 4) void lngemm_kernel(
    const float* __restrict__ x, const float* __restrict__ gw, const float* __restrict__ bw,
    const u16* __restrict__ Wc, u16* __restrict__ kg, u16* __restrict__ vtg)
{
  __shared__ u16 sh[16384];   // 32KB: A [64][256] swz  |  vT [256][64] swz
  const int t = threadIdx.x, w = t >> 6, lane = t & 63;
  const int L15 = lane & 15, q4 = lane >> 4;
  const int blk = blockIdx.x;

  float4 gv = *(const float4*)(gw + lane*4);
  float4 bv = *(const float4*)(bw + lane*4);
  // ---- LN: 16 rows/wave, 2 groups of 8 for ILP ----
  #pragma unroll
  for (int grp = 0; grp < 2; ++grp) {
    float4 xv[8]; float s[8], sq[8];
    #pragma unroll
    for (int i = 0; i < 8; ++i) {
      int m = w*16 + grp*8 + i;
      xv[i] = *(const float4*)(x + ((size_t)(blk*64 + m))*256 + lane*4);
    }
    #pragma unroll
    for (int i = 0; i < 8; ++i) {
      s[i]  = xv[i].x + xv[i].y + xv[i].z + xv[i].w;
      sq[i] = xv[i].x*xv[i].x + xv[i].y*xv[i].y + xv[i].z*xv[i].z + xv[i].w*xv[i].w;
    }
    #pragma unroll
    for (int mm = 32; mm >= 1; mm >>= 1)
      #pragma unroll
      for (int i = 0; i < 8; ++i) {
        s[i]  += __shfl_xor(s[i],  mm, 64);
        sq[i] += __shfl_xor(sq[i], mm, 64);
      }
    #pragma unroll
    for (int i = 0; i < 8; ++i) {
      int m = w*16 + grp*8 + i;
      float mean = s[i] * (1.f/256.f);
      float rstd = rsqrtf(sq[i] * (1.f/256.f) - mean*mean + 1e-5f);
      ushort4 o;
      o.x = f2bf((xv[i].x - mean)*rstd*gv.x + bv.x);
      o.y = f2bf((xv[i].y - mean)*rstd*gv.y + bv.y);
      o.z = f2bf((xv[i].z - mean)*rstd*gv.z + bv.z);
      o.w = f2bf((xv[i].w - mean)*rstd*gv.w + bv.w);
      int swz = (lane >> 1) ^ (m & 7);
      *(ushort4*)&sh[m*256 + swz*8 + (lane & 1)*4] = o;
    }
  }
  __syncthreads();   // barrier 1: A-tile ready

  f32x4 acc[4][4];   // [j coltile][mt]
  // ---- phase 0: k-half (coltiles j*4+w), phase 1: v-half ----
  #pragma unroll
  for (int p = 0; p < 2; ++p) {
    #pragma unroll
    for (int j = 0; j < 4; ++j)
      #pragma unroll
      for (int mt = 0; mt < 4; ++mt)
        acc[j][mt] = (f32x4){0.f, 0.f, 0.f, 0.f};
    for (int ks = 0; ks < 8; ++ks) {
      bf16x8 bf[4], af[4];
      #pragma unroll
      for (int j = 0; j < 4; ++j) {
        int col = (p*16 + j*4 + w)*16 + L15;
        bf[j] = *(const bf16x8*)(Wc + (size_t)col*256 + ks*32 + q4*8);
      }
      #pragma unroll
      for (int mt = 0; mt < 4; ++mt)
        af[mt] = *(const bf16x8*)&sh[(mt*16 + L15)*256 + (((ks*4 + q4) ^ (L15 & 7)) << 3)];
      #pragma unroll
      for (int j = 0; j < 4; ++j)
        #pragma unroll
        for (int mt = 0; mt < 4; ++mt)
          acc[j][mt] = __builtin_amdgcn_mfma_f32_16x16x32_bf16(af[mt], bf[j], acc[j][mt], 0, 0, 0);
    }
    if (p == 0) {
      // k epilogue: direct scalar stores (coalesced across L15)
      #pragma unroll
      for (int j = 0; j < 4; ++j) {
        int col = (j*4 + w)*16 + L15;
        #pragma unroll
        for (int mt = 0; mt < 4; ++mt)
          #pragma unroll
          for (int r = 0; r < 4; ++r) {
            size_t row = (size_t)blk*64 + mt*16 + q4*4 + r;
            kg[row*256 + col] = f2bf(acc[j][mt][r]);
          }
      }
    }
  }
  __syncthreads();   // barrier 2: all waves done reading A-tile
  // ---- v epilogue: stage [d][n] into sh (XOR swizzle), packed b64 writes ----
  #pragma unroll
  for (int j = 0; j < 4; ++j) {
    int d = (j*4 + w)*16 + L15;
    #pragma unroll
    for (int mt = 0; mt < 4; ++mt) {
      int c = mt*2 + (q4 >> 1);
      u32 lo = (u32)f2bf(acc[j][mt][0]) | ((u32)f2bf(acc[j][mt][1]) << 16);
      u32 hi = (u32)f2bf(acc[j][mt][2]) | ((u32)f2bf(acc[j][mt][3]) << 16);
      u32* p32 = (u32*)&sh[d*64 + ((c ^ (d & 7)) << 3) + (q4 & 1)*4];
      p32[0] = lo; p32[1] = hi;
    }
  }
  __syncthreads();   // barrier 3: vT staged
  {
    int bb = blk >> 6;
    int nbase = (blk & 63)*64;
    #pragma unroll
    for (int i = 0; i < 8; ++i) {
      int d = i*32 + w*8 + (lane >> 3);
      int c = lane & 7;
      uint4 vv = *(const uint4*)&sh[d*64 + ((c ^ (d & 7)) << 3)];
      *(uint4*)(vtg + (size_t)bb*1048576 + (size_t)d*4096 + nbase + c*8) = vv;
    }
  }
}

// ---------------- K3: q = LN(slots)@Wq^T -> bf16 (unchanged) ----------------
__global__ __launch_bounds__(256) void q_kernel(
    const float* __restrict__ slots, const float* __restrict__ gw, const float* __restrict__ bw,
    const float* __restrict__ WqT, u16* __restrict__ qbf)
{
  __shared__ float ln[2][256];
  int t = threadIdx.x, wv = t >> 6, lane = t & 63;
  int base = blockIdx.x * 2;
  if (wv < 2) {
    int row = base + wv;
    float4 xv = *(const float4*)(slots + (size_t)row*256 + lane*4);
    float s  = xv.x + xv.y + xv.z + xv.w;
    float sq = xv.x*xv.x + xv.y*xv.y + xv.z*xv.z + xv.w*xv.w;
    #pragma unroll
    for (int m = 32; m >= 1; m >>= 1) { s += __shfl_xor(s, m, 64); sq += __shfl_xor(sq, m, 64); }
    float mean = s * (1.f/256.f);
    float rstd = rsqrtf(sq * (1.f/256.f) - mean*mean + 1e-5f);
    float4 gv = *(const float4*)(gw + lane*4);
    float4 bv = *(const float4*)(bw + lane*4);
    ln[wv][lane*4+0] = (xv.x - mean)*rstd*gv.x + bv.x;
    ln[wv][lane*4+1] = (xv.y - mean)*rstd*gv.y + bv.y;
    ln[wv][lane*4+2] = (xv.z - mean)*rstd*gv.z + bv.z;
    ln[wv][lane*4+3] = (xv.w - mean)*rstd*gv.w + bv.w;
  }
  __syncthreads();
  float a0 = 0.f, a1 = 0.f;
  for (int d = 0; d < 256; ++d) {
    float w = WqT[d*256 + t];
    a0 += ln[0][d] * w;
    a1 += ln[1][d] * w;
  }
  qbf[(size_t)base*256 + t]     = f2bf(a0);
  qbf[(size_t)(base+1)*256 + t] = f2bf(a1);
}

// ---------------- K4: attn v3 — stream k/vT as MFMA frags, 1 barrier ----------------
// grid (64 b, 32 cg); block covers 128 n. No big LDS tiles.
__global__ __launch_bounds__(256, 4) void attn_kernel(
    const u16* __restrict__ kg, const u16* __restrict__ vtg, const u16* __restrict__ qbf,
    float* __restrict__ updp, float* __restrict__ sums_p)
{
  __shared__ u16 attnT[8*128];    // [slot][n] bf16, XOR-swizzled chunks of 8
  __shared__ float sums_w[4][8];
  const int b = blockIdx.x, cg = blockIdx.y;
  const int t = threadIdx.x, w = t >> 6, lane = t & 63;
  const int L15 = lane & 15, q4 = lane >> 4;
  const int n0 = cg*128;
  const int slot = L15 & 7;

  // q B-frags (8 ksteps x 8 bf16); cols 8..15 duplicate slots 0..7 (harmless)
  bf16x8 qf[8];
  {
    const u16* qp = qbf + ((size_t)b*8 + slot)*256;
    #pragma unroll
    for (int ks = 0; ks < 8; ++ks)
      qf[ks] = *(const bf16x8*)(qp + ks*32 + q4*8);
  }

  // ---- logits: 2 m-tiles/wave, A-frags streamed from k ----
  f32x4 lg[2] = {};
  #pragma unroll
  for (int mt = 0; mt < 2; ++mt) {
    const u16* krow = kg + ((size_t)(b*4096 + n0 + mt*64 + w*16 + L15))*256;
    #pragma unroll
    for (int ks = 0; ks < 8; ++ks) {
      bf16x8 af = *(const bf16x8*)(krow + ks*32 + q4*8);
      lg[mt] = __builtin_amdgcn_mfma_f32_16x16x32_bf16(af, qf[ks], lg[mt], 0, 0, 0);
    }
  }
  // ---- softmax over slots (lanes L15 bits 0..2) + attnT staging + col sums ----
  float tot = 0.f;
  #pragma unroll
  for (int mt = 0; mt < 2; ++mt) {
    float av[4];
    #pragma unroll
    for (int r = 0; r < 4; ++r) {
      float val = lg[mt][r];
      float mx = val;
      mx = fmaxf(mx, __shfl_xor(mx, 1, 64));
      mx = fmaxf(mx, __shfl_xor(mx, 2, 64));
      mx = fmaxf(mx, __shfl_xor(mx, 4, 64));
      float e = expf(val - mx);
      float se = e;
      se += __shfl_xor(se, 1, 64);
      se += __shfl_xor(se, 2, 64);
      se += __shfl_xor(se, 4, 64);
      av[r] = e / se + EPSA;
      tot += av[r];
    }
    if (L15 < 8) {
      int c = mt*8 + w*2 + (q4 >> 1);
      u32 lo = (u32)f2bf(av[0]) | ((u32)f2bf(av[1]) << 16);
      u32 hi = (u32)f2bf(av[2]) | ((u32)f2bf(av[3]) << 16);
      u32* p32 = (u32*)&attnT[slot*128 + ((c ^ (slot*2)) << 3) + (q4 & 1)*4];
      p32[0] = lo; p32[1] = hi;
    }
  }
  tot += __shfl_xor(tot, 16, 64);
  tot += __shfl_xor(tot, 32, 64);
  if (q4 == 0 && L15 < 8) sums_w[w][L15] = tot;
  __syncthreads();   // the ONE barrier

  // ---- PV: A = attnT (LDS), B = vT frags streamed from global ----
  f32x4 accp[4] = {};
  for (int ks = 0; ks < 4; ++ks) {
    int c = ks*4 + q4;
    bf16x8 pa = *(const bf16x8*)&attnT[slot*128 + ((c ^ (slot*2)) << 3)];
    #pragma unroll
    for (int nt = 0; nt < 4; ++nt) {
      int d = (nt*4 + w)*16 + L15;
      bf16x8 vb = *(const bf16x8*)(vtg + (size_t)b*1048576 + (size_t)d*4096 + n0 + ks*32 + q4*8);
      accp[nt] = __builtin_amdgcn_mfma_f32_16x16x32_bf16(pa, vb, accp[nt], 0, 0, 0);
    }
  }
  // store partials: rows = slots (q4<2), cols = d
  if (q4 < 2) {
    float* up = updp + ((size_t)(b*NCG + cg))*2048;
    #pragma unroll
    for (int nt = 0; nt < 4; ++nt) {
      int d = (nt*4 + w)*16 + L15;
      #pragma unroll
      for (int r = 0; r < 4; ++r)
        up[(q4*4 + r)*256 + d] = accp[nt][r];
    }
  }
  if (t < 8)
    sums_p[(b*NCG + cg)*8 + t] = sums_w[0][t] + sums_w[1][t] + sums_w[2][t] + sums_w[3][t];
}

// ---------------- K5: partial-reduce + GRU + (optional) MLP ----------------
__global__ __launch_bounds__(256) void grumlp_kernel(
    const float* __restrict__ updp, const float* __restrict__ sums_p,
    const float* __restrict__ WihT, const float* __restrict__ WhhT,
    const float* __restrict__ bih, const float* __restrict__ bhh,
    const float* __restrict__ gm, const float* __restrict__ bm,
    const float* __restrict__ W1T, const float* __restrict__ b1,
    const float* __restrict__ W2T, const float* __restrict__ b2,
    float* __restrict__ slots, int do_mlp)
{
  __shared__ float xs[4][256], hs[4][256];
  __shared__ float ln[4][256];
  __shared__ float hb[4][512];
  int t = threadIdx.x, w = t >> 6, lane = t & 63;
  int base = blockIdx.x * 4;
  #pragma unroll
  for (int g = 0; g < 4; ++g) {
    int row = base + g;
    int b = row >> 3, s = row & 7;
    float u = 0.f, sm = 0.f;
    for (int c = 0; c < NCG; ++c) {
      u  += updp[((size_t)(b*NCG + c)*8 + s)*256 + t];
      sm += sums_p[(b*NCG + c)*8 + s];
    }
    xs[g][t] = u / sm;
    hs[g][t] = slots[(size_t)row*256 + t];
  }
  __syncthreads();
  float ra[4] = {}, za[4] = {}, ia[4] = {}, ha[4] = {};
  for (int d = 0; d < 256; ++d) {
    float wir = WihT[d*768 + t], wiz = WihT[d*768 + 256 + t], win = WihT[d*768 + 512 + t];
    float whr = WhhT[d*768 + t], whz = WhhT[d*768 + 256 + t], whn = WhhT[d*768 + 512 + t];
    #pragma unroll
    for (int g = 0; g < 4; ++g) {
      float xx = xs[g][d], hh = hs[g][d];
      ra[g] += xx*wir + hh*whr;
      za[g] += xx*wiz + hh*whz;
      ia[g] += xx*win;
      ha[g] += hh*whn;
    }
  }
  float bir = bih[t], biz = bih[256+t], bin = bih[512+t];
  float bhr = bhh[t], bhz = bhh[256+t], bhn = bhh[512+t];
  float nv[4];
  #pragma unroll
  for (int g = 0; g < 4; ++g) {
    float r  = 1.f/(1.f + expf(-(ra[g] + bir + bhr)));
    float z  = 1.f/(1.f + expf(-(za[g] + biz + bhz)));
    float nn = tanhf(ia[g] + bin + r*(ha[g] + bhn));
    nv[g] = (1.f - z)*nn + z*hs[g][t];
  }
  if (!do_mlp) {
    #pragma unroll
    for (int g = 0; g < 4; ++g)
      slots[(size_t)(base+g)*256 + t] = nv[g];
    return;
  }
  #pragma unroll
  for (int g = 0; g < 4; ++g) xs[g][t] = nv[g];
  __syncthreads();
  {
    float4 xv = *(const float4*)&xs[w][lane*4];
    float s  = xv.x + xv.y + xv.z + xv.w;
    float sq = xv.x*xv.x + xv.y*xv.y + xv.z*xv.z + xv.w*xv.w;
    #pragma unroll
    for (int m = 32; m >= 1; m >>= 1) { s += __shfl_xor(s, m, 64); sq += __shfl_xor(sq, m, 64); }
    float mean = s * (1.f/256.f);
    float rstd = rsqrtf(sq * (1.f/256.f) - mean*mean + 1e-5f);
    float4 gv = *(const float4*)(gm + lane*4);
    float4 bv = *(const float4*)(bm + lane*4);
    ln[w][lane*4+0] = (xv.x - mean)*rstd*gv.x + bv.x;
    ln[w][lane*4+1] = (xv.y - mean)*rstd*gv.y + bv.y;
    ln[w][lane*4+2] = (xv.z - mean)*rstd*gv.z + bv.z;
    ln[w][lane*4+3] = (xv.w - mean)*rstd*gv.w + bv.w;
  }
  __syncthreads();
  float h0[4] = {}, h1[4] = {};
  for (int d = 0; d < 256; ++d) {
    float w0 = W1T[d*512 + t], w1 = W1T[d*512 + 256 + t];
    #pragma unroll
    for (int g = 0; g < 4; ++g) { float l = ln[g][d]; h0[g] += l*w0; h1[g] += l*w1; }
  }
  float bb0 = b1[t], bb1 = b1[256 + t];
  #pragma unroll
  for (int g = 0; g < 4; ++g) {
    hb[g][t]       = fmaxf(h0[g] + bb0, 0.f);
    hb[g][256 + t] = fmaxf(h1[g] + bb1, 0.f);
  }
  __syncthreads();
  float o[4] = {};
  for (int hh = 0; hh < 512; ++hh) {
    float ww = W2T[hh*256 + t];
    #pragma unroll
    for (int g = 0; g < 4; ++g) o[g] += hb[g][hh] * ww;
  }
  float b2v = b2[t];
  #pragma unroll
  for (int g = 0; g < 4; ++g)
    slots[(size_t)(base+g)*256 + t] = xs[g][t] + o[g] + b2v;
}

// ---------------- host ----------------
extern "C" void kernel_launch(void* const* d_in, const int* in_sizes, int n_in,
                              void* d_out, int out_size, void* d_ws, size_t ws_size,
                              hipStream_t stream)
{
  (void)in_sizes; (void)n_in; (void)out_size; (void)ws_size;
  const float* inputs = (const float*)d_in[0];
  const float* noise  = (const float*)d_in[1];
  const float* mu     = (const float*)d_in[2];
  const float* lsig   = (const float*)d_in[3];
  const float* g_in   = (const float*)d_in[4];
  const float* b_in   = (const float*)d_in[5];
  const float* g_sl   = (const float*)d_in[6];
  const float* b_sl   = (const float*)d_in[7];
  const float* g_mlp  = (const float*)d_in[8];
  const float* b_mlp  = (const float*)d_in[9];
  const float* Wq     = (const float*)d_in[10];
  const float* Wk     = (const float*)d_in[11];
  const float* Wv     = (const float*)d_in[12];
  const float* Wih    = (const float*)d_in[13];
  const float* Whh    = (const float*)d_in[14];
  const float* bih    = (const float*)d_in[15];
  const float* bhh    = (const float*)d_in[16];
  const float* W1     = (const float*)d_in[17];
  const float* b1     = (const float*)d_in[18];
  const float* W2     = (const float*)d_in[19];
  const float* b2     = (const float*)d_in[20];

  char* ws = (char*)d_ws;
  u16*   kg     = (u16*)  (ws + OFF_KG);
  u16*   vtg    = (u16*)  (ws + OFF_VTG);
  float* slots  = (float*)(ws + OFF_SLOTS);
  u16*   qb     = (u16*)  (ws + OFF_QBF);
  float* updp   = (float*)(ws + OFF_UPDP);
  float* sums_p = (float*)(ws + OFF_SUMSP);
  u16*   Wc     = (u16*)  (ws + OFF_WC);
  float* WqT    = (float*)(ws + OFF_WQT);
  float* WihT   = (float*)(ws + OFF_WIHT);
  float* WhhT   = (float*)(ws + OFF_WHHT);
  float* W1T    = (float*)(ws + OFF_W1T);
  float* W2T    = (float*)(ws + OFF_W2T);

  prep_kernel<<<768, 256, 0, stream>>>(Wq, Wk, Wv, Wih, Whh, W1, W2,
                                       Wc, WqT, WihT, WhhT, W1T, W2T);
  slots_init_kernel<<<512, 256, 0, stream>>>(noise, mu, lsig, slots);
  lngemm_kernel<<<NROW/64, 256, 0, stream>>>(inputs, g_in, b_in, Wc, kg, vtg);

  for (int it = 0; it < 3; ++it) {
    q_kernel<<<NSLOT/2, 256, 0, stream>>>(slots, g_sl, b_sl, WqT, qb);
    attn_kernel<<<dim3(NB, NCG), 256, 0, stream>>>(kg, vtg, qb, updp, sums_p);
    grumlp_kernel<<<NSLOT/4, 256, 0, stream>>>(updp, sums_p, WihT, WhhT, bih, bhh,
                                               g_mlp, b_mlp, W1T, b1, W2T, b2,
                                               slots, (it < 2) ? 1 : 0);
  }
  hipMemcpyAsync(d_out, slots, (size_t)NSLOT*NS*sizeof(float),
                 hipMemcpyDeviceToDevice, stream);
}